// Round 3
// baseline (414.680 us; speedup 1.0000x reference)
//
#include <hip/hip_runtime.h>
#include <math.h>

// Problem constants (B=4, S=4096, D=2048, E=64, K=8)
#define NTOK   16384      // B*S
#define DDIM   2048
#define NE     64
#define TOPK   8

#define THREADS 512
#define NWAVE   8
#define TOKPB   32        // tokens per block -> 512 blocks -> 2 resident/CU
#define BK      128       // K-chunk staged per iteration
#define NCHUNK (DDIM / BK)     // 16
#define KSLICE (BK / NWAVE)    // 16 k per wave per chunk

// x tile XOR swizzle (tile width 32 tokens): logical (k,t) at k*32 + (t ^ SWZ)
// with SWZ = ((k>>2)&7)<<2. Staging stores: bank = r + 4*(w ^ (k4&7)) -> every
// bank exactly 2 lanes = free. Compute reads: all lanes share k, 8 distinct
// b128 addrs (8-way broadcast) -> conflict-free. float4 alignment preserved.
#define XSWZ(k)  ((((k) >> 2) & 7) << 2)

// scoreBuf swizzle: logical [t][e] stored at t*67 + (e ^ (t&7))
#define SBIDX(t,e) ((t)*67 + ((e) ^ ((t) & 7)))

__global__ __launch_bounds__(THREADS, 4) void gate_kernel(
    const float* __restrict__ x, const float* __restrict__ W,
    const float* __restrict__ b, float* __restrict__ out)
{
    // 48 KiB LDS: ldsX = smem[0..4095]    (swizzled [BK][32] k-major x tile)
    //             ldsW = smem[4096..12287] ([BK][64], same layout as global)
    // scoreBuf [32][67] (2144 floats) aliases smem[0..2143] after main loop.
    __shared__ float smem[12288];

    const int tid  = threadIdx.x;
    const int wave = tid >> 6;
    const int lane = tid & 63;
    const int tg   = lane >> 3;   // token group 0..7 -> tokens tg*4..tg*4+3
    const int eg   = lane & 7;    // expert group 0..7 -> experts eg*8..eg*8+7
    const int tok0 = blockIdx.x * TOKPB;

    float acc[4][8];
#pragma unroll
    for (int i = 0; i < 4; ++i)
#pragma unroll
        for (int j = 0; j < 8; ++j) acc[i][j] = 0.f;

    const int kw0 = wave * KSLICE;
    // x staging map: 16 threads per token row; st_t = tid>>4 (0..31),
    // st_k4 = tid&15, jj in {0,1} -> k4 = st_k4 + 16*jj (0..31). Coalesced 256B.
    const int st_t  = tid >> 4;
    const int st_k4 = tid & 15;
    const float* xrow = &x[(size_t)(tok0 + st_t) * DDIM];

    // ---- prologue: prefetch chunk 0 into registers ----
    float4 rx[2], rw[4];
#pragma unroll
    for (int jj = 0; jj < 2; ++jj)
        rx[jj] = *(const float4*)&xrow[(st_k4 + jj * 16) * 4];
#pragma unroll
    for (int jj = 0; jj < 4; ++jj)
        rw[jj] = ((const float4*)W)[tid + jj * THREADS];

    for (int c = 0; c < NCHUNK; ++c) {
        __syncthreads();   // previous chunk fully consumed
        // ---- store prefetched regs -> LDS (transpose x with swizzle) ----
#pragma unroll
        for (int jj = 0; jj < 2; ++jj) {
            const int k4   = st_k4 + jj * 16;         // 0..31
            const int base = st_t ^ ((k4 & 7) << 2);  // = st_t ^ XSWZ(k4*4+i)
            const float4 v = rx[jj];
            smem[(k4 * 4 + 0) * 32 + base] = v.x;
            smem[(k4 * 4 + 1) * 32 + base] = v.y;
            smem[(k4 * 4 + 2) * 32 + base] = v.z;
            smem[(k4 * 4 + 3) * 32 + base] = v.w;
        }
#pragma unroll
        for (int jj = 0; jj < 4; ++jj)
            *(float4*)&smem[4096 + (tid + jj * THREADS) * 4] = rw[jj];

        // ---- issue next chunk's global loads (overlap with compute) ----
        if (c + 1 < NCHUNK) {
            const int kc = (c + 1) * BK;
#pragma unroll
            for (int jj = 0; jj < 2; ++jj)
                rx[jj] = *(const float4*)&xrow[kc + (st_k4 + jj * 16) * 4];
#pragma unroll
            for (int jj = 0; jj < 4; ++jj)
                rw[jj] = *(const float4*)&W[(size_t)kc * NE + (tid + jj * THREADS) * 4];
        }
        __syncthreads();

        // ---- compute: this wave's k slice, 4x8 outer product per lane ----
#pragma unroll
        for (int kk = 0; kk < KSLICE; ++kk) {
            const int k    = kw0 + kk;
            const int xoff = k * 32 + ((tg * 4) ^ XSWZ(k));
            const float4 xa = *(const float4*)&smem[xoff];
            const float4 wa = *(const float4*)&smem[4096 + k * 64 + eg * 8];
            const float4 wb = *(const float4*)&smem[4096 + k * 64 + eg * 8 + 4];
            const float xs[4] = {xa.x, xa.y, xa.z, xa.w};
            const float ws[8] = {wa.x, wa.y, wa.z, wa.w, wb.x, wb.y, wb.z, wb.w};
#pragma unroll
            for (int i = 0; i < 4; ++i)
#pragma unroll
                for (int j = 0; j < 8; ++j)
                    acc[i][j] = fmaf(xs[i], ws[j], acc[i][j]);
        }
    }

    // ---- cross-wave reduction into swizzled scoreBuf (aliases ldsX) ----
    __syncthreads();
    for (int s = tid; s < TOKPB * 67; s += THREADS) smem[s] = 0.f;
    __syncthreads();
#pragma unroll
    for (int i = 0; i < 4; ++i)
#pragma unroll
        for (int j = 0; j < 8; ++j) {
            const int t = tg * 4 + i;
            const int e = eg * 8 + j;
            atomicAdd(&smem[SBIDX(t, e)], acc[i][j]);
        }
    __syncthreads();

    float* out_g   = out;                           // [16384][8]
    float* out_idx = out + (size_t)NTOK * TOPK;     // [16384][8] (as float)
    float* out_s   = out + (size_t)NTOK * TOPK * 2; // [16384][64]

    // ---- sigmoid + store scores; overwrite scoreBuf with sigmoid ----
#pragma unroll
    for (int r = 0; r < 4; ++r) {
        const int flat = r * THREADS + tid;     // 0..2047
        const int t = flat >> 6;
        const int e = flat & 63;
        const float z = smem[SBIDX(t, e)] + b[e];
        const float s = 1.f / (1.f + expf(-z));
        out_s[(size_t)tok0 * NE + flat] = s;
        smem[SBIDX(t, e)] = s;
    }
    __syncthreads();

    // ---- top-8 per token (strict > picks lowest index on ties, matching
    // jax.lax.top_k) ----
    if (tid < TOKPB) {
        const int t = tid;
        float gv[TOPK];
        int   gi[TOPK];
        float sum = 0.f;
#pragma unroll
        for (int j = 0; j < TOPK; ++j) {
            float best = -1.f;
            int bi = 0;
            for (int e = 0; e < NE; ++e) {
                const float v = smem[SBIDX(t, e)];
                if (v > best) { best = v; bi = e; }
            }
            gv[j] = best; gi[j] = bi; sum += best;
            smem[SBIDX(t, bi)] = -2.f;  // sigmoid in (0,1), so excluded
        }
        const float inv = 1.f / sum;
#pragma unroll
        for (int j = 0; j < TOPK; ++j) {
            out_g[(size_t)(tok0 + t) * TOPK + j]   = gv[j] * inv;
            out_idx[(size_t)(tok0 + t) * TOPK + j] = (float)gi[j];
        }
    }
}

extern "C" void kernel_launch(void* const* d_in, const int* in_sizes, int n_in,
                              void* d_out, int out_size, void* d_ws, size_t ws_size,
                              hipStream_t stream) {
    const float* x = (const float*)d_in[0];
    const float* W = (const float*)d_in[1];
    const float* b = (const float*)d_in[2];
    // d_in[3] is k (==8), compile-time constant here.
    float* out = (float*)d_out;
    gate_kernel<<<NTOK / TOKPB, THREADS, 0, stream>>>(x, W, b, out);
}

// Round 4
// 328.626 us; speedup vs baseline: 1.2619x; 1.2619x over previous
//
#include <hip/hip_runtime.h>
#include <math.h>

// Problem constants (B=4, S=4096, D=2048, E=64, K=8)
#define NTOK   16384      // B*S
#define DDIM   2048
#define NE     64
#define TOPK   8

#define THREADS 512
#define NWAVE   8
#define TOKPB   32        // tokens per block -> 512 blocks -> 2 resident/CU
#define BK      128       // K-chunk staged per iteration
#define NCHUNK (DDIM / BK)     // 16
#define KSLICE (BK / NWAVE)    // 16 k per wave per chunk

// x tile XOR swizzle (tile width 32 tokens): logical (k,t) at k*32 + (t ^ SWZ)
// with SWZ = ((k>>2)&7)<<2. Staging stores: every bank exactly 2 lanes = free.
// Compute reads: 8 distinct b128 addrs, 8-way broadcast -> conflict-free.
#define XSWZ(k)  ((((k) >> 2) & 7) << 2)

// scoreBuf swizzle: logical [t][e] stored at t*67 + (e ^ (t&7))
#define SBIDX(t,e) ((t)*67 + ((e) ^ ((t) & 7)))

// launch_bounds: R3 showed the 2nd arg behaves CUDA-style (min BLOCKS/CU):
// (512,4) forced VGPR=64 -> 550 MB scratch spill traffic. (512,2) caps
// VGPR at 128 >= the ~85 this kernel needs -> no spills, still 2 blocks/CU.
__global__ __launch_bounds__(THREADS, 2) void gate_kernel(
    const float* __restrict__ x, const float* __restrict__ W,
    const float* __restrict__ b, float* __restrict__ out)
{
    // 48 KiB LDS: ldsX = smem[0..4095]    (swizzled [BK][32] k-major x tile)
    //             ldsW = smem[4096..12287] ([BK][64], same layout as global)
    // scoreBuf [32][67] (2144 floats) aliases smem[0..2143] after main loop.
    __shared__ float smem[12288];

    const int tid  = threadIdx.x;
    const int wave = tid >> 6;
    const int lane = tid & 63;
    const int tg   = lane >> 3;   // token group 0..7 -> tokens tg*4..tg*4+3
    const int eg   = lane & 7;    // expert group 0..7 -> experts eg*8..eg*8+7
    const int tok0 = blockIdx.x * TOKPB;

    float acc[4][8];
#pragma unroll
    for (int i = 0; i < 4; ++i)
#pragma unroll
        for (int j = 0; j < 8; ++j) acc[i][j] = 0.f;

    const int kw0 = wave * KSLICE;
    // x staging map: 16 threads per token row; st_t = tid>>4 (0..31),
    // st_k4 = tid&15, jj in {0,1} -> k4 = st_k4 + 16*jj (0..31). Coalesced 256B.
    const int st_t  = tid >> 4;
    const int st_k4 = tid & 15;
    const float* xrow = &x[(size_t)(tok0 + st_t) * DDIM];

    // ---- prologue: prefetch chunk 0 into registers ----
    float4 rx[2], rw[4];
#pragma unroll
    for (int jj = 0; jj < 2; ++jj)
        rx[jj] = *(const float4*)&xrow[(st_k4 + jj * 16) * 4];
#pragma unroll
    for (int jj = 0; jj < 4; ++jj)
        rw[jj] = ((const float4*)W)[tid + jj * THREADS];

    for (int c = 0; c < NCHUNK; ++c) {
        __syncthreads();   // previous chunk fully consumed
        // ---- store prefetched regs -> LDS (transpose x with swizzle) ----
#pragma unroll
        for (int jj = 0; jj < 2; ++jj) {
            const int k4   = st_k4 + jj * 16;         // 0..31
            const int base = st_t ^ ((k4 & 7) << 2);  // = st_t ^ XSWZ(k4*4+i)
            const float4 v = rx[jj];
            smem[(k4 * 4 + 0) * 32 + base] = v.x;
            smem[(k4 * 4 + 1) * 32 + base] = v.y;
            smem[(k4 * 4 + 2) * 32 + base] = v.z;
            smem[(k4 * 4 + 3) * 32 + base] = v.w;
        }
#pragma unroll
        for (int jj = 0; jj < 4; ++jj)
            *(float4*)&smem[4096 + (tid + jj * THREADS) * 4] = rw[jj];

        // ---- issue next chunk's global loads (overlap with compute) ----
        if (c + 1 < NCHUNK) {
            const int kc = (c + 1) * BK;
#pragma unroll
            for (int jj = 0; jj < 2; ++jj)
                rx[jj] = *(const float4*)&xrow[kc + (st_k4 + jj * 16) * 4];
#pragma unroll
            for (int jj = 0; jj < 4; ++jj)
                rw[jj] = *(const float4*)&W[(size_t)kc * NE + (tid + jj * THREADS) * 4];
        }
        __syncthreads();

        // ---- compute: this wave's k slice, 4x8 outer product per lane ----
#pragma unroll
        for (int kk = 0; kk < KSLICE; ++kk) {
            const int k    = kw0 + kk;
            const int xoff = k * 32 + ((tg * 4) ^ XSWZ(k));
            const float4 xa = *(const float4*)&smem[xoff];
            const float4 wa = *(const float4*)&smem[4096 + k * 64 + eg * 8];
            const float4 wb = *(const float4*)&smem[4096 + k * 64 + eg * 8 + 4];
            const float xs[4] = {xa.x, xa.y, xa.z, xa.w};
            const float ws[8] = {wa.x, wa.y, wa.z, wa.w, wb.x, wb.y, wb.z, wb.w};
#pragma unroll
            for (int i = 0; i < 4; ++i)
#pragma unroll
                for (int j = 0; j < 8; ++j)
                    acc[i][j] = fmaf(xs[i], ws[j], acc[i][j]);
        }
    }

    // ---- cross-wave reduction into swizzled scoreBuf (aliases ldsX) ----
    __syncthreads();
    for (int s = tid; s < TOKPB * 67; s += THREADS) smem[s] = 0.f;
    __syncthreads();
#pragma unroll
    for (int i = 0; i < 4; ++i)
#pragma unroll
        for (int j = 0; j < 8; ++j) {
            const int t = tg * 4 + i;
            const int e = eg * 8 + j;
            atomicAdd(&smem[SBIDX(t, e)], acc[i][j]);
        }
    __syncthreads();

    float* out_g   = out;                           // [16384][8]
    float* out_idx = out + (size_t)NTOK * TOPK;     // [16384][8] (as float)
    float* out_s   = out + (size_t)NTOK * TOPK * 2; // [16384][64]

    // ---- sigmoid + store scores; overwrite scoreBuf with sigmoid ----
#pragma unroll
    for (int r = 0; r < 4; ++r) {
        const int flat = r * THREADS + tid;     // 0..2047
        const int t = flat >> 6;
        const int e = flat & 63;
        const float z = smem[SBIDX(t, e)] + b[e];
        const float s = 1.f / (1.f + expf(-z));
        out_s[(size_t)tok0 * NE + flat] = s;
        smem[SBIDX(t, e)] = s;
    }
    __syncthreads();

    // ---- top-8 per token (strict > picks lowest index on ties, matching
    // jax.lax.top_k) ----
    if (tid < TOKPB) {
        const int t = tid;
        float gv[TOPK];
        int   gi[TOPK];
        float sum = 0.f;
#pragma unroll
        for (int j = 0; j < TOPK; ++j) {
            float best = -1.f;
            int bi = 0;
            for (int e = 0; e < NE; ++e) {
                const float v = smem[SBIDX(t, e)];
                if (v > best) { best = v; bi = e; }
            }
            gv[j] = best; gi[j] = bi; sum += best;
            smem[SBIDX(t, bi)] = -2.f;  // sigmoid in (0,1), so excluded
        }
        const float inv = 1.f / sum;
#pragma unroll
        for (int j = 0; j < TOPK; ++j) {
            out_g[(size_t)(tok0 + t) * TOPK + j]   = gv[j] * inv;
            out_idx[(size_t)(tok0 + t) * TOPK + j] = (float)gi[j];
        }
    }
}

extern "C" void kernel_launch(void* const* d_in, const int* in_sizes, int n_in,
                              void* d_out, int out_size, void* d_ws, size_t ws_size,
                              hipStream_t stream) {
    const float* x = (const float*)d_in[0];
    const float* W = (const float*)d_in[1];
    const float* b = (const float*)d_in[2];
    // d_in[3] is k (==8), compile-time constant here.
    float* out = (float*)d_out;
    gate_kernel<<<NTOK / TOKPB, THREADS, 0, stream>>>(x, W, b, out);
}

// Round 5
// 262.153 us; speedup vs baseline: 1.5818x; 1.2536x over previous
//
#include <hip/hip_runtime.h>
#include <math.h>
#include <stdint.h>

// Problem constants (B=4, S=4096, D=2048, E=64, K=8)
#define NTOK   16384      // B*S
#define DDIM   2048
#define NE     64
#define TOPK   8

#define THREADS 512
#define NWAVE   8
#define TOKPB   32        // tokens per block -> 512 blocks -> 2 resident/CU
#define BK      64        // K-chunk per stage
#define NCHUNK  (DDIM / BK)   // 32
#define KSLICE  (BK / NWAVE)  // 8 k per wave per chunk

// float4 slots per buffer: x tile [k4 0..15][sigma(t) 0..31], W tile [k][e4]
#define XSLOTS   ((BK / 4) * TOKPB)   // 512  (8 KiB)
#define WSLOTS   (BK * (NE / 4))      // 1024 (16 KiB)
#define BUFSLOTS (XSLOTS + WSLOTS)    // 1536 (24 KiB); x2 buffers = 48 KiB

// scoreBuf swizzle: logical [t][e] stored at t*67 + (e ^ (t&7))
#define SBIDX(t,e) ((t)*67 + ((e) ^ ((t) & 7)))

// Async global->LDS DMA, 16 B per lane. LDS dest is wave-uniform base +
// lane*16 (m104/m108) -- all per-lane layout choice happens on the global
// address side. AS casts via uintptr_t (generic LDS addr low 32 bits = LDS
// offset on AMDGPU).
__device__ __forceinline__ void gl_lds16(const void* g, void* l) {
    __builtin_amdgcn_global_load_lds(
        (const __attribute__((address_space(1))) void*)(uintptr_t)g,
        (__attribute__((address_space(3))) void*)(uintptr_t)l,
        16, 0, 0);
}

__global__ __launch_bounds__(THREADS, 2) void gate_kernel(
    const float* __restrict__ x, const float* __restrict__ W,
    const float* __restrict__ b, float* __restrict__ out)
{
    __shared__ float4 smem[2 * BUFSLOTS];   // 48 KiB

    const int tid  = threadIdx.x;
    const int wave = tid >> 6;
    const int lane = tid & 63;
    const int tg   = lane >> 3;   // token group 0..7 -> tokens tg*4..tg*4+3
    const int eg   = lane & 7;    // expert group 0..7 -> experts eg*8..eg*8+7
    const int tok0 = blockIdx.x * TOKPB;

    // ---- staging source addresses (per-lane constants) ----
    // x: lds slot s = wave*64 + lane; k4 = s>>5 (=tid>>5), sig = lane&31,
    //    t = 4*(sig&7) + (sig>>3). So slot k4*32 + (tg + 8*i) holds
    //    x[4*tg+i][4*k4 .. 4*k4+3]  -> compute reads hit 8 distinct
    //    bank-quads (conflict-free).
    const int st_k4 = tid >> 5;                 // 0..15
    const int st_sg = lane & 31;
    const int st_t  = 4 * (st_sg & 7) + (st_sg >> 3);
    const float* gx  = x + (size_t)(tok0 + st_t) * DDIM + st_k4 * 4;
    // W: lds slot s2 = XSLOTS + wave*128 + j*64 + lane; layout [k][e4]
    //    matches global row-major exactly -> linear, fully coalesced.
    const float* gw0 = W + (size_t)(wave * 128 + lane) * 4;
    const float* gw1 = gw0 + 64 * 4;

    float acc[4][8];
#pragma unroll
    for (int i = 0; i < 4; ++i)
#pragma unroll
        for (int j = 0; j < 8; ++j) acc[i][j] = 0.f;

    // stage chunk c into buffer c&1 (3 async 16B DMAs per lane, no VGPRs)
    auto stage = [&](int c) {
        float4* B = &smem[(c & 1) * BUFSLOTS];
        const int kc = c * BK;
        gl_lds16(gx + kc,             &B[wave * 64]);
        gl_lds16(gw0 + (size_t)kc * NE, &B[XSLOTS + wave * 128]);
        gl_lds16(gw1 + (size_t)kc * NE, &B[XSLOTS + wave * 128 + 64]);
    };

    stage(0);
    __syncthreads();   // vmcnt drain -> buffer 0 ready

    for (int c = 0; c < NCHUNK; ++c) {
        if (c + 1 < NCHUNK) stage(c + 1);   // async into the other buffer
        const float4* BX = &smem[(c & 1) * BUFSLOTS];
        const float4* BW = BX + XSLOTS;
#pragma unroll
        for (int g = 0; g < 2; ++g) {
            const int k4 = wave * 2 + g;    // this wave's k4 pair
            float4 xv[4];
#pragma unroll
            for (int i = 0; i < 4; ++i)
                xv[i] = BX[k4 * 32 + tg + 8 * i];   // x[4tg+i][4k4..4k4+3]
#pragma unroll
            for (int kk = 0; kk < 4; ++kk) {
                const int k = k4 * 4 + kk;
                const float4 wa = BW[k * 16 + eg * 2];
                const float4 wb = BW[k * 16 + eg * 2 + 1];
                const float ws[8] = {wa.x, wa.y, wa.z, wa.w,
                                     wb.x, wb.y, wb.z, wb.w};
#pragma unroll
                for (int i = 0; i < 4; ++i) {
                    const float xs = ((const float*)&xv[i])[kk];
#pragma unroll
                    for (int j = 0; j < 8; ++j)
                        acc[i][j] = fmaf(xs, ws[j], acc[i][j]);
                }
            }
        }
        __syncthreads();   // all waves done with buf c; buf c+1 DMA drained
    }

    // ---- cross-wave reduction into swizzled scoreBuf (aliases smem) ----
    float* sb = (float*)smem;
    for (int s = tid; s < TOKPB * 67; s += THREADS) sb[s] = 0.f;
    __syncthreads();
#pragma unroll
    for (int i = 0; i < 4; ++i)
#pragma unroll
        for (int j = 0; j < 8; ++j)
            atomicAdd(&sb[SBIDX(tg * 4 + i, eg * 8 + j)], acc[i][j]);
    __syncthreads();

    float* out_g   = out;                           // [16384][8]
    float* out_idx = out + (size_t)NTOK * TOPK;     // [16384][8] (as float)
    float* out_s   = out + (size_t)NTOK * TOPK * 2; // [16384][64]

    // ---- sigmoid + store scores; overwrite scoreBuf with sigmoid ----
#pragma unroll
    for (int r = 0; r < (TOKPB * NE) / THREADS; ++r) {
        const int flat = r * THREADS + tid;     // 0..2047
        const int t = flat >> 6;
        const int e = flat & 63;
        const float z = sb[SBIDX(t, e)] + b[e];
        const float s = 1.f / (1.f + expf(-z));
        out_s[(size_t)tok0 * NE + flat] = s;
        sb[SBIDX(t, e)] = s;
    }
    __syncthreads();

    // ---- top-8 per token (strict > picks lowest index on ties, matching
    // jax.lax.top_k) ----
    if (tid < TOKPB) {
        const int t = tid;
        float gv[TOPK];
        int   gi[TOPK];
        float sum = 0.f;
#pragma unroll
        for (int j = 0; j < TOPK; ++j) {
            float best = -1.f;
            int bi = 0;
            for (int e = 0; e < NE; ++e) {
                const float v = sb[SBIDX(t, e)];
                if (v > best) { best = v; bi = e; }
            }
            gv[j] = best; gi[j] = bi; sum += best;
            sb[SBIDX(t, bi)] = -2.f;  // sigmoid in (0,1), so excluded
        }
        const float inv = 1.f / sum;
#pragma unroll
        for (int j = 0; j < TOPK; ++j) {
            out_g[(size_t)(tok0 + t) * TOPK + j]   = gv[j] * inv;
            out_idx[(size_t)(tok0 + t) * TOPK + j] = (float)gi[j];
        }
    }
}

extern "C" void kernel_launch(void* const* d_in, const int* in_sizes, int n_in,
                              void* d_out, int out_size, void* d_ws, size_t ws_size,
                              hipStream_t stream) {
    const float* x = (const float*)d_in[0];
    const float* W = (const float*)d_in[1];
    const float* b = (const float*)d_in[2];
    // d_in[3] is k (==8), compile-time constant here.
    float* out = (float*)d_out;
    gate_kernel<<<NTOK / TOKPB, THREADS, 0, stream>>>(x, W, b, out);
}